// Round 1
// baseline (6981.745 us; speedup 1.0000x reference)
//
#include <hip/hip_runtime.h>

// GCN 6-layer, N=100k nodes, E=3.2M edges.
// Strategy: fold symmetric norm into y = dis .* x; aggregate on the narrow
// side of each layer; atomic-scatter edges; block-per-node matmul with LDS
// row staging; two-stage min/max; normalize.

#define TPB 256

__global__ void deg_kernel(const int* __restrict__ dst, int E, float* __restrict__ deg) {
    int e = blockIdx.x * blockDim.x + threadIdx.x;
    if (e < E) atomicAdd(&deg[dst[e]], 1.0f);
}

// in-place: deg -> rsqrt(deg + 1)   (the +1 is the self-loop)
__global__ void dis_kernel(float* __restrict__ dis, int n) {
    int i = blockIdx.x * blockDim.x + threadIdx.x;
    if (i < n) dis[i] = rsqrtf(dis[i] + 1.0f);
}

// agg1[dst] += dis[src]  (scalar aggregation for layer 1, x == ones)
__global__ void scat1_kernel(const int* __restrict__ src, const int* __restrict__ dst,
                             int E, const float* __restrict__ dis, float* __restrict__ agg1) {
    int e = blockIdx.x * blockDim.x + threadIdx.x;
    if (e < E) atomicAdd(&agg1[dst[e]], dis[src[e]]);
}

// y1[i][j] = dis[i] * ( b1[j] + W1[j] * dis[i]*(agg1[i] + dis[i]) )
__global__ void layer1_kernel(const float* __restrict__ dis, const float* __restrict__ agg1,
                              const float* __restrict__ W1, const float* __restrict__ b1,
                              float* __restrict__ y1, int n) {
    int idx = blockIdx.x * blockDim.x + threadIdx.x;
    if (idx >= n * 25) return;
    int i = idx / 25;
    int j = idx - i * 25;
    float d = dis[i];
    float s = d * (agg1[i] + d);          // sum of norm over incoming edges incl self
    float x1 = b1[j] + W1[j] * s;
    y1[idx] = d * x1;
}

// agg[dst*dim+k] += y[src*dim+k]   for all edges, k in [0,dim)
__global__ void scat_kernel(const int* __restrict__ src, const int* __restrict__ dst,
                            int E, int dim, const float* __restrict__ y, float* __restrict__ agg) {
    long long idx = (long long)blockIdx.x * blockDim.x + threadIdx.x;
    if (idx >= (long long)E * dim) return;
    int e = (int)(idx / dim);
    int k = (int)(idx - (long long)e * dim);
    atomicAdd(&agg[(long long)dst[e] * dim + k], y[(long long)src[e] * dim + k]);
}

// one block per node: in[k] = dis[i]*(agg[i][k] + y[i][k]); out row = dis[i]*(b + in @ W)
__global__ void mm_kernel(const float* __restrict__ y, const float* __restrict__ agg,
                          const float* __restrict__ dis,
                          const float* __restrict__ W, const float* __restrict__ b,
                          float* __restrict__ yout, int din, int dout) {
    __shared__ float sIn[128];
    int i = blockIdx.x;
    int t = threadIdx.x;
    float d = dis[i];
    if (t < din) sIn[t] = d * (agg[(long long)i * din + t] + y[(long long)i * din + t]);
    __syncthreads();
    if (t < dout) {
        float acc = b[t];
        for (int k = 0; k < din; ++k)
            acc += sIn[k] * W[k * dout + t];
        yout[(long long)i * dout + t] = d * acc;   // pre-scale for next layer's y
    }
}

// g[i] = sum_k y5[i][k] * W6[k]
__global__ void g6_kernel(const float* __restrict__ y5, const float* __restrict__ W6,
                          float* __restrict__ g, int n) {
    int i = blockIdx.x * blockDim.x + threadIdx.x;
    if (i >= n) return;
    const float* row = y5 + (long long)i * 125;
    float acc = 0.f;
#pragma unroll 5
    for (int k = 0; k < 125; ++k) acc += row[k] * W6[k];
    g[i] = acc;
}

__global__ void scat6_kernel(const int* __restrict__ src, const int* __restrict__ dst,
                             int E, const float* __restrict__ g, float* __restrict__ agg6) {
    int e = blockIdx.x * blockDim.x + threadIdx.x;
    if (e < E) atomicAdd(&agg6[dst[e]], g[src[e]]);
}

// v[i] = b6 + dis[i]*(agg6[i] + g[i])
__global__ void final6_kernel(const float* __restrict__ dis, const float* __restrict__ agg6,
                              const float* __restrict__ g, const float* __restrict__ b6,
                              float* __restrict__ v, int n) {
    int i = blockIdx.x * blockDim.x + threadIdx.x;
    if (i < n) v[i] = b6[0] + dis[i] * (agg6[i] + g[i]);
}

__global__ void minmax_part_kernel(const float* __restrict__ v, int n,
                                   float* __restrict__ bmin, float* __restrict__ bmax) {
    __shared__ float smn[TPB], smx[TPB];
    int t = threadIdx.x;
    float mn = 1e30f, mx = -1e30f;
    for (int i = blockIdx.x * blockDim.x + t; i < n; i += gridDim.x * blockDim.x) {
        float x = v[i];
        mn = fminf(mn, x);
        mx = fmaxf(mx, x);
    }
    smn[t] = mn; smx[t] = mx;
    __syncthreads();
    for (int s = TPB / 2; s > 0; s >>= 1) {
        if (t < s) { smn[t] = fminf(smn[t], smn[t + s]); smx[t] = fmaxf(smx[t], smx[t + s]); }
        __syncthreads();
    }
    if (t == 0) { bmin[blockIdx.x] = smn[0]; bmax[blockIdx.x] = smx[0]; }
}

__global__ void minmax_final_kernel(const float* __restrict__ bmin, const float* __restrict__ bmax,
                                    int nblk, float* __restrict__ mnmx) {
    __shared__ float smn[TPB], smx[TPB];
    int t = threadIdx.x;
    float mn = 1e30f, mx = -1e30f;
    for (int i = t; i < nblk; i += TPB) {
        mn = fminf(mn, bmin[i]);
        mx = fmaxf(mx, bmax[i]);
    }
    smn[t] = mn; smx[t] = mx;
    __syncthreads();
    for (int s = TPB / 2; s > 0; s >>= 1) {
        if (t < s) { smn[t] = fminf(smn[t], smn[t + s]); smx[t] = fmaxf(smx[t], smx[t + s]); }
        __syncthreads();
    }
    if (t == 0) { mnmx[0] = smn[0]; mnmx[1] = smx[0]; }
}

__global__ void normalize_kernel(const float* __restrict__ v, const float* __restrict__ mnmx,
                                 float* __restrict__ out, int n) {
    int i = blockIdx.x * blockDim.x + threadIdx.x;
    if (i < n) {
        float mn = mnmx[0], mx = mnmx[1];
        out[i] = (v[i] - mn) / (mx - mn + 1e-15f);
    }
}

static inline int cdiv(long long a, int b) { return (int)((a + b - 1) / b); }

extern "C" void kernel_launch(void* const* d_in, const int* in_sizes, int n_in,
                              void* d_out, int out_size, void* d_ws, size_t ws_size,
                              hipStream_t stream) {
    const int N = out_size;               // 100000
    const int E = in_sizes[0] / 2;        // 3200000
    const int* src = (const int*)d_in[0];
    const int* dst = src + E;

    const float* W1 = (const float*)d_in[1];  const float* b1 = (const float*)d_in[2];
    const float* W2 = (const float*)d_in[3];  const float* b2 = (const float*)d_in[4];
    const float* W3 = (const float*)d_in[5];  const float* b3 = (const float*)d_in[6];
    const float* W4 = (const float*)d_in[7];  const float* b4 = (const float*)d_in[8];
    const float* W5 = (const float*)d_in[9];  const float* b5 = (const float*)d_in[10];
    const float* W6 = (const float*)d_in[11]; const float* b6 = (const float*)d_in[12];

    // workspace layout (floats)
    float* ws = (float*)d_ws;
    float* dis   = ws;                 ws += N;          // deg -> dis in place
    float* agg1  = ws;                 ws += N;
    float* bufA  = ws;                 ws += (long long)N * 125;
    float* bufB  = ws;                 ws += (long long)N * 125;
    float* aggB  = ws;                 ws += (long long)N * 125;
    float* g     = ws;                 ws += N;
    float* agg6  = ws;                 ws += N;
    float* v     = ws;                 ws += N;
    float* bmin  = ws;                 ws += TPB;
    float* bmax  = ws;                 ws += TPB;
    float* mnmx  = ws;                 ws += 2;

    // degree + dis
    hipMemsetAsync(dis, 0, (size_t)N * 4, stream);
    deg_kernel<<<cdiv(E, TPB), TPB, 0, stream>>>(dst, E, dis);
    dis_kernel<<<cdiv(N, TPB), TPB, 0, stream>>>(dis, N);

    // layer 1 (1 -> 25): scalar aggregation
    hipMemsetAsync(agg1, 0, (size_t)N * 4, stream);
    scat1_kernel<<<cdiv(E, TPB), TPB, 0, stream>>>(src, dst, E, dis, agg1);
    layer1_kernel<<<cdiv((long long)N * 25, TPB), TPB, 0, stream>>>(dis, agg1, W1, b1, bufA, N);

    // layer 2 (25 -> 125): aggregate 25 dims, then matmul
    hipMemsetAsync(aggB, 0, (size_t)N * 25 * 4, stream);
    scat_kernel<<<cdiv((long long)E * 25, TPB), TPB, 0, stream>>>(src, dst, E, 25, bufA, aggB);
    mm_kernel<<<N, 128, 0, stream>>>(bufA, aggB, dis, W2, b2, bufB, 25, 125);

    // layers 3..5 (125 -> 125)
    const float* Ws[3] = {W3, W4, W5};
    const float* bs[3] = {b3, b4, b5};
    float* yin = bufB;
    float* yout = bufA;
    for (int L = 0; L < 3; ++L) {
        hipMemsetAsync(aggB, 0, (size_t)N * 125 * 4, stream);
        scat_kernel<<<cdiv((long long)E * 125, TPB), TPB, 0, stream>>>(src, dst, E, 125, yin, aggB);
        mm_kernel<<<N, 128, 0, stream>>>(yin, aggB, dis, Ws[L], bs[L], yout, 125, 125);
        float* tmp = yin; yin = yout; yout = tmp;
    }
    // yin now holds y5

    // layer 6 (125 -> 1): matmul first, scalar aggregation
    g6_kernel<<<cdiv(N, TPB), TPB, 0, stream>>>(yin, W6, g, N);
    hipMemsetAsync(agg6, 0, (size_t)N * 4, stream);
    scat6_kernel<<<cdiv(E, TPB), TPB, 0, stream>>>(src, dst, E, g, agg6);
    final6_kernel<<<cdiv(N, TPB), TPB, 0, stream>>>(dis, agg6, g, b6, v, N);

    // min-max normalize
    minmax_part_kernel<<<TPB, TPB, 0, stream>>>(v, N, bmin, bmax);
    minmax_final_kernel<<<1, TPB, 0, stream>>>(bmin, bmax, TPB, mnmx);
    normalize_kernel<<<cdiv(N, TPB), TPB, 0, stream>>>(v, mnmx, (float*)d_out, N);
}

// Round 2
// 2268.700 us; speedup vs baseline: 3.0774x; 3.0774x over previous
//
#include <hip/hip_runtime.h>

// GCN 6-layer, N=100k, E=3.2M. Round 1: CSR (by dst) + gather aggregation,
// fused aggregate+matmul per layer, 8 nodes per block. No float atomics.

#define TPB 256
#define RN 8   // nodes per block in fused layer kernels

// ---------- CSR build ----------
__global__ void deg_int_kernel(const int* __restrict__ dst, int E, int* __restrict__ degi) {
    int e = blockIdx.x * blockDim.x + threadIdx.x;
    if (e < E) atomicAdd(&degi[dst[e]], 1);
}

__global__ void scan_part(const int* __restrict__ degi, int n, int* __restrict__ bsum) {
    __shared__ int s[TPB];
    int t = threadIdx.x;
    int i = blockIdx.x * TPB + t;
    s[t] = (i < n) ? degi[i] : 0;
    __syncthreads();
    for (int off = TPB / 2; off > 0; off >>= 1) {
        if (t < off) s[t] += s[t + off];
        __syncthreads();
    }
    if (t == 0) bsum[blockIdx.x] = s[0];
}

__global__ void scan_bsum(int* bsum, int nb) {
    if (threadIdx.x == 0 && blockIdx.x == 0) {
        int run = 0;
        for (int j = 0; j < nb; ++j) { int v = bsum[j]; bsum[j] = run; run += v; }
    }
}

// exclusive scan within block + block offset -> rowptr, cursor; also dis = rsqrt(deg+1)
__global__ void scan_final(const int* __restrict__ degi, int n,
                           const int* __restrict__ bsum,
                           int* __restrict__ rowptr, int* __restrict__ cursor,
                           float* __restrict__ dis) {
    __shared__ int s[TPB];
    int t = threadIdx.x;
    int i = blockIdx.x * TPB + t;
    int d = (i < n) ? degi[i] : 0;
    s[t] = d;
    __syncthreads();
    for (int off = 1; off < TPB; off <<= 1) {
        int add = (t >= off) ? s[t - off] : 0;
        __syncthreads();
        s[t] += add;
        __syncthreads();
    }
    if (i < n) {
        int ex = bsum[blockIdx.x] + s[t] - d;   // exclusive prefix
        rowptr[i] = ex;
        cursor[i] = ex;
        dis[i] = rsqrtf((float)d + 1.0f);       // +1 = self-loop
        if (i == n - 1) rowptr[n] = bsum[blockIdx.x] + s[t];
    }
}

__global__ void fill_csr(const int* __restrict__ src, const int* __restrict__ dst, int E,
                         int* __restrict__ cursor, int* __restrict__ csr) {
    int e = blockIdx.x * blockDim.x + threadIdx.x;
    if (e < E) {
        int pos = atomicAdd(&cursor[dst[e]], 1);
        csr[pos] = src[e];
    }
}

// ---------- scalar gathers (layers 1 and 6) ----------
// out[i] = sum over in-edges of val[src]; one wave per node
__global__ void gather_scalar(const float* __restrict__ val,
                              const int* __restrict__ rowptr, const int* __restrict__ csr,
                              float* __restrict__ out, int n) {
    int w = (blockIdx.x * blockDim.x + threadIdx.x) >> 6;
    int lane = threadIdx.x & 63;
    if (w >= n) return;
    int beg = rowptr[w], end = rowptr[w + 1];
    float acc = 0.f;
    for (int e = beg + lane; e < end; e += 64) acc += val[csr[e]];
    for (int off = 32; off > 0; off >>= 1) acc += __shfl_down(acc, off);
    if (lane == 0) out[w] = acc;
}

// y1[i*32+j] = dis[i] * (b1[j] + W1[j] * dis[i]*(agg1[i] + dis[i]))   (x == ones)
__global__ void layer1_kernel(const float* __restrict__ dis, const float* __restrict__ agg1,
                              const float* __restrict__ W1, const float* __restrict__ b1,
                              float* __restrict__ y1, int n) {
    int idx = blockIdx.x * blockDim.x + threadIdx.x;
    if (idx >= n * 32) return;
    int i = idx >> 5;
    int j = idx & 31;
    if (j >= 25) return;
    float d = dis[i];
    float s = d * (agg1[i] + d);
    y1[idx] = d * (b1[j] + W1[j] * s);
}

// ---------- fused aggregate + matmul, din=25 -> dout=125 ----------
__global__ __launch_bounds__(128) void layer25_kernel(
    const float* __restrict__ y,          // N x 32 (cols 0..24 valid), pre-scaled by dis
    const int* __restrict__ rowptr, const int* __restrict__ csr,
    const float* __restrict__ dis,
    const float* __restrict__ W,          // 25 x 125
    const float* __restrict__ b,
    float* __restrict__ yout, int n) {    // N x 128
    __shared__ float part[RN][4][32];
    __shared__ float sIn[RN][26];
    int t = threadIdx.x;
    int k = t & 31, g = t >> 5;           // 4 edge-groups of 32 lanes
    int base = blockIdx.x * RN;
    for (int r = 0; r < RN; ++r) {
        int i = base + r;
        float acc = 0.f;
        if (i < n && k < 25) {
            int beg = rowptr[i], end = rowptr[i + 1];
            if (g == 0) acc = y[(size_t)i * 32 + k];          // self-loop
            for (int e = beg + g; e < end; e += 4)
                acc += y[(size_t)csr[e] * 32 + k];
        }
        part[r][g][k] = acc;
    }
    __syncthreads();
    if (g == 0 && k < 25) {
        for (int r = 0; r < RN; ++r) {
            int i = base + r;
            float s_ = part[r][0][k] + part[r][1][k] + part[r][2][k] + part[r][3][k];
            sIn[r][k] = (i < n) ? dis[i] * s_ : 0.f;
        }
    }
    __syncthreads();
    if (t < 125) {
        float o[RN];
        float bt = b[t];
#pragma unroll
        for (int r = 0; r < RN; ++r) o[r] = bt;
        for (int kk = 0; kk < 25; ++kk) {
            float w = W[kk * 125 + t];
#pragma unroll
            for (int r = 0; r < RN; ++r) o[r] += sIn[r][kk] * w;
        }
#pragma unroll
        for (int r = 0; r < RN; ++r) {
            int i = base + r;
            if (i < n) yout[(size_t)i * 128 + t] = dis[i] * o[r];
        }
    }
}

// ---------- fused aggregate + matmul, din=125 -> dout=125 ----------
__global__ __launch_bounds__(128) void layer125_kernel(
    const float* __restrict__ y,          // N x 128 (cols 0..124 valid), pre-scaled by dis
    const int* __restrict__ rowptr, const int* __restrict__ csr,
    const float* __restrict__ dis,
    const float* __restrict__ W,          // 125 x 125
    const float* __restrict__ b,
    float* __restrict__ yout, int n) {    // N x 128
    __shared__ float sIn[RN][128];
    int t = threadIdx.x;
    int base = blockIdx.x * RN;
    for (int r = 0; r < RN; ++r) {
        int i = base + r;
        if (i >= n) break;
        float acc = 0.f;
        if (t < 125) {
            acc = y[(size_t)i * 128 + t];                      // self-loop
            int beg = rowptr[i], end = rowptr[i + 1];
            for (int e = beg; e < end; ++e) {
                int s = csr[e];
                acc += y[(size_t)s * 128 + t];
            }
            sIn[r][t] = dis[i] * acc;
        }
    }
    __syncthreads();
    if (t < 125) {
        float o[RN];
        float bt = b[t];
#pragma unroll
        for (int r = 0; r < RN; ++r) o[r] = bt;
        for (int kk = 0; kk < 125; ++kk) {
            float w = W[kk * 125 + t];
#pragma unroll
            for (int r = 0; r < RN; ++r) o[r] += sIn[r][kk] * w;
        }
#pragma unroll
        for (int r = 0; r < RN; ++r) {
            int i = base + r;
            if (i < n) yout[(size_t)i * 128 + t] = dis[i] * o[r];
        }
    }
}

// ---------- layer 6 ----------
__global__ void g6_kernel(const float* __restrict__ y5, const float* __restrict__ W6,
                          float* __restrict__ g, int n) {
    int i = blockIdx.x * blockDim.x + threadIdx.x;
    if (i >= n) return;
    const float* row = y5 + (size_t)i * 128;
    float acc = 0.f;
#pragma unroll 5
    for (int k = 0; k < 125; ++k) acc += row[k] * W6[k];
    g[i] = acc;
}

__global__ void final6_kernel(const float* __restrict__ dis, const float* __restrict__ agg6,
                              const float* __restrict__ g, const float* __restrict__ b6,
                              float* __restrict__ v, int n) {
    int i = blockIdx.x * blockDim.x + threadIdx.x;
    if (i < n) v[i] = b6[0] + dis[i] * (agg6[i] + g[i]);
}

// ---------- min-max normalize ----------
__global__ void minmax_part_kernel(const float* __restrict__ v, int n,
                                   float* __restrict__ bmin, float* __restrict__ bmax) {
    __shared__ float smn[TPB], smx[TPB];
    int t = threadIdx.x;
    float mn = 1e30f, mx = -1e30f;
    for (int i = blockIdx.x * blockDim.x + t; i < n; i += gridDim.x * blockDim.x) {
        float x = v[i];
        mn = fminf(mn, x);
        mx = fmaxf(mx, x);
    }
    smn[t] = mn; smx[t] = mx;
    __syncthreads();
    for (int s = TPB / 2; s > 0; s >>= 1) {
        if (t < s) { smn[t] = fminf(smn[t], smn[t + s]); smx[t] = fmaxf(smx[t], smx[t + s]); }
        __syncthreads();
    }
    if (t == 0) { bmin[blockIdx.x] = smn[0]; bmax[blockIdx.x] = smx[0]; }
}

__global__ void minmax_final_kernel(const float* __restrict__ bmin, const float* __restrict__ bmax,
                                    int nblk, float* __restrict__ mnmx) {
    __shared__ float smn[TPB], smx[TPB];
    int t = threadIdx.x;
    float mn = 1e30f, mx = -1e30f;
    for (int i = t; i < nblk; i += TPB) {
        mn = fminf(mn, bmin[i]);
        mx = fmaxf(mx, bmax[i]);
    }
    smn[t] = mn; smx[t] = mx;
    __syncthreads();
    for (int s = TPB / 2; s > 0; s >>= 1) {
        if (t < s) { smn[t] = fminf(smn[t], smn[t + s]); smx[t] = fmaxf(smx[t], smx[t + s]); }
        __syncthreads();
    }
    if (t == 0) { mnmx[0] = smn[0]; mnmx[1] = smx[0]; }
}

__global__ void normalize_kernel(const float* __restrict__ v, const float* __restrict__ mnmx,
                                 float* __restrict__ out, int n) {
    int i = blockIdx.x * blockDim.x + threadIdx.x;
    if (i < n) {
        float mn = mnmx[0], mx = mnmx[1];
        out[i] = (v[i] - mn) / (mx - mn + 1e-15f);
    }
}

static inline int cdiv(long long a, int b) { return (int)((a + b - 1) / b); }

extern "C" void kernel_launch(void* const* d_in, const int* in_sizes, int n_in,
                              void* d_out, int out_size, void* d_ws, size_t ws_size,
                              hipStream_t stream) {
    const int N = out_size;               // 100000
    const int E = in_sizes[0] / 2;        // 3200000
    const int* src = (const int*)d_in[0];
    const int* dst = src + E;

    const float* W1 = (const float*)d_in[1];  const float* b1 = (const float*)d_in[2];
    const float* W2 = (const float*)d_in[3];  const float* b2 = (const float*)d_in[4];
    const float* W3 = (const float*)d_in[5];  const float* b3 = (const float*)d_in[6];
    const float* W4 = (const float*)d_in[7];  const float* b4 = (const float*)d_in[8];
    const float* W5 = (const float*)d_in[9];  const float* b5 = (const float*)d_in[10];
    const float* W6 = (const float*)d_in[11]; const float* b6 = (const float*)d_in[12];

    const int nb = cdiv(N, TPB);          // scan blocks (391)

    // workspace layout
    char* p = (char*)d_ws;
    int*   degi   = (int*)p;   p += (size_t)N * 4;
    int*   rowptr = (int*)p;   p += (size_t)(N + 1) * 4;
    int*   cursor = (int*)p;   p += (size_t)N * 4;
    int*   bsum   = (int*)p;   p += (size_t)(nb + 1) * 4;
    int*   csr    = (int*)p;   p += (size_t)E * 4;
    float* dis    = (float*)p; p += (size_t)N * 4;
    float* agg1   = (float*)p; p += (size_t)N * 4;
    float* buf25  = (float*)p; p += (size_t)N * 32 * 4;
    float* bufA   = (float*)p; p += (size_t)N * 128 * 4;
    float* bufB   = (float*)p; p += (size_t)N * 128 * 4;
    float* g      = (float*)p; p += (size_t)N * 4;
    float* agg6   = (float*)p; p += (size_t)N * 4;
    float* v      = (float*)p; p += (size_t)N * 4;
    float* bmin   = (float*)p; p += (size_t)TPB * 4;
    float* bmax   = (float*)p; p += (size_t)TPB * 4;
    float* mnmx   = (float*)p; p += 2 * 4;

    // ---- CSR build ----
    hipMemsetAsync(degi, 0, (size_t)N * 4, stream);
    deg_int_kernel<<<cdiv(E, TPB), TPB, 0, stream>>>(dst, E, degi);
    scan_part<<<nb, TPB, 0, stream>>>(degi, N, bsum);
    scan_bsum<<<1, 1, 0, stream>>>(bsum, nb);
    scan_final<<<nb, TPB, 0, stream>>>(degi, N, bsum, rowptr, cursor, dis);
    fill_csr<<<cdiv(E, TPB), TPB, 0, stream>>>(src, dst, E, cursor, csr);

    // ---- layer 1 (1 -> 25): scalar gather of dis ----
    gather_scalar<<<cdiv((long long)N * 64, TPB), TPB, 0, stream>>>(dis, rowptr, csr, agg1, N);
    layer1_kernel<<<cdiv((long long)N * 32, TPB), TPB, 0, stream>>>(dis, agg1, W1, b1, buf25, N);

    // ---- layer 2 (25 -> 125) ----
    layer25_kernel<<<cdiv(N, RN), 128, 0, stream>>>(buf25, rowptr, csr, dis, W2, b2, bufB, N);

    // ---- layers 3..5 (125 -> 125) ----
    layer125_kernel<<<cdiv(N, RN), 128, 0, stream>>>(bufB, rowptr, csr, dis, W3, b3, bufA, N);
    layer125_kernel<<<cdiv(N, RN), 128, 0, stream>>>(bufA, rowptr, csr, dis, W4, b4, bufB, N);
    layer125_kernel<<<cdiv(N, RN), 128, 0, stream>>>(bufB, rowptr, csr, dis, W5, b5, bufA, N);

    // ---- layer 6 (125 -> 1) ----
    g6_kernel<<<cdiv(N, TPB), TPB, 0, stream>>>(bufA, W6, g, N);
    gather_scalar<<<cdiv((long long)N * 64, TPB), TPB, 0, stream>>>(g, rowptr, csr, agg6, N);
    final6_kernel<<<cdiv(N, TPB), TPB, 0, stream>>>(dis, agg6, g, b6, v, N);

    // ---- min-max normalize ----
    minmax_part_kernel<<<TPB, TPB, 0, stream>>>(v, N, bmin, bmax);
    minmax_final_kernel<<<1, TPB, 0, stream>>>(bmin, bmax, TPB, mnmx);
    normalize_kernel<<<cdiv(N, TPB), TPB, 0, stream>>>(v, mnmx, (float*)d_out, N);
}

// Round 3
// 585.430 us; speedup vs baseline: 11.9258x; 3.8753x over previous
//
#include <hip/hip_runtime.h>

// GCN 6-layer, N=100k, E=3.2M — Krylov reformulation.
// No nonlinearity in the reference => network is linear:
//   x_{l+1} = A_norm x_l W_l + 1 b_l^T,  x_1 = ones(N,1)
// => output v = sum_{k=0..6} c_k * p_k,  p_k = A_norm^k 1,
// where c_k are scalars from chained small matvecs of W/b.
// Node side: 6 scalar gather-aggregations over CSR (0.4MB value buffer,
// L2-resident). Feature side: one tiny single-block coefficient kernel.

#define TPB 256

// ---------- CSR build ----------
__global__ void deg_int_kernel(const int* __restrict__ dst, int E, int* __restrict__ degi) {
    int e = blockIdx.x * blockDim.x + threadIdx.x;
    if (e < E) atomicAdd(&degi[dst[e]], 1);
}

__global__ void scan_part(const int* __restrict__ degi, int n, int* __restrict__ bsum) {
    __shared__ int s[TPB];
    int t = threadIdx.x;
    int i = blockIdx.x * TPB + t;
    s[t] = (i < n) ? degi[i] : 0;
    __syncthreads();
    for (int off = TPB / 2; off > 0; off >>= 1) {
        if (t < off) s[t] += s[t + off];
        __syncthreads();
    }
    if (t == 0) bsum[blockIdx.x] = s[0];
}

// single-block exclusive scan of block sums (nb <= 512 for N=100k, TPB=256)
__global__ void scan_bsum_block(int* __restrict__ bsum, int nb) {
    __shared__ int s[512];
    int t = threadIdx.x;
    int v = (t < nb) ? bsum[t] : 0;
    s[t] = v;
    __syncthreads();
    for (int off = 1; off < 512; off <<= 1) {
        int add = (t >= off) ? s[t - off] : 0;
        __syncthreads();
        s[t] += add;
        __syncthreads();
    }
    if (t < nb) bsum[t] = s[t] - v;   // exclusive
}

// exclusive scan within block + block offset -> rowptr, cursor; dis = rsqrt(deg+1)
__global__ void scan_final(const int* __restrict__ degi, int n,
                           const int* __restrict__ bsum,
                           int* __restrict__ rowptr, int* __restrict__ cursor,
                           float* __restrict__ dis) {
    __shared__ int s[TPB];
    int t = threadIdx.x;
    int i = blockIdx.x * TPB + t;
    int d = (i < n) ? degi[i] : 0;
    s[t] = d;
    __syncthreads();
    for (int off = 1; off < TPB; off <<= 1) {
        int add = (t >= off) ? s[t - off] : 0;
        __syncthreads();
        s[t] += add;
        __syncthreads();
    }
    if (i < n) {
        int ex = bsum[blockIdx.x] + s[t] - d;   // exclusive prefix
        rowptr[i] = ex;
        cursor[i] = ex;
        dis[i] = rsqrtf((float)d + 1.0f);       // +1 = self-loop
        if (i == n - 1) rowptr[n] = bsum[blockIdx.x] + s[t];
    }
}

__global__ void fill_csr(const int* __restrict__ src, const int* __restrict__ dst, int E,
                         int* __restrict__ cursor, int* __restrict__ csr) {
    int e = blockIdx.x * blockDim.x + threadIdx.x;
    if (e < E) {
        int pos = atomicAdd(&cursor[dst[e]], 1);
        csr[pos] = src[e];
    }
}

// ---------- coefficient chain (feature side), one block of 128 ----------
// a_{l+1,k+1} = W_l^T a_{l,k};  a_{l+1,0} = b_l;  c_k = a_{7,k}
__global__ void coef_kernel(const float* __restrict__ W1, const float* __restrict__ b1,
                            const float* __restrict__ W2, const float* __restrict__ b2,
                            const float* __restrict__ W3, const float* __restrict__ b3,
                            const float* __restrict__ W4, const float* __restrict__ b4,
                            const float* __restrict__ W5, const float* __restrict__ b5,
                            const float* __restrict__ W6, const float* __restrict__ b6,
                            float* __restrict__ c) {
    __shared__ float A[6][125];
    __shared__ float B[6][125];
    __shared__ float red[128];
    int t = threadIdx.x;   // 128 threads
    // after layer 1: x2 = p1 * W1^T + p0 * b1^T   (dims 25)
    if (t < 25) { A[1][t] = W1[t]; A[0][t] = b1[t]; }
    __syncthreads();
    // layer 2 (25 -> 125)
    if (t < 125) {
        for (int k = 0; k < 2; ++k) {
            float s = 0.f;
            for (int i = 0; i < 25; ++i) s += W2[i * 125 + t] * A[k][i];
            B[k + 1][t] = s;
        }
        B[0][t] = b2[t];
    }
    __syncthreads();
    // layer 3
    if (t < 125) {
        for (int k = 0; k < 3; ++k) {
            float s = 0.f;
            for (int i = 0; i < 125; ++i) s += W3[i * 125 + t] * B[k][i];
            A[k + 1][t] = s;
        }
        A[0][t] = b3[t];
    }
    __syncthreads();
    // layer 4
    if (t < 125) {
        for (int k = 0; k < 4; ++k) {
            float s = 0.f;
            for (int i = 0; i < 125; ++i) s += W4[i * 125 + t] * A[k][i];
            B[k + 1][t] = s;
        }
        B[0][t] = b4[t];
    }
    __syncthreads();
    // layer 5
    if (t < 125) {
        for (int k = 0; k < 5; ++k) {
            float s = 0.f;
            for (int i = 0; i < 125; ++i) s += W5[i * 125 + t] * B[k][i];
            A[k + 1][t] = s;
        }
        A[0][t] = b5[t];
    }
    __syncthreads();
    // layer 6 (125 -> 1): c[k+1] = W6 . A[k]
    float w6 = (t < 125) ? W6[t] : 0.f;
    for (int k = 0; k < 6; ++k) {
        red[t] = (t < 125) ? w6 * A[k][t] : 0.f;
        __syncthreads();
        for (int off = 64; off > 0; off >>= 1) {
            if (t < off) red[t] += red[t + off];
            __syncthreads();
        }
        if (t == 0) c[k + 1] = red[0];
        __syncthreads();
    }
    if (t == 0) c[0] = b6[0];
}

// ---------- scalar aggregation step ----------
// p[i] = dis_i * (sum_{in-edges} q[src] + q[i]);  qnext = dis .* p;
// vacc += c[k] * p   (vacc = c[0] on first step, since p0 = 1)
__global__ void gather_step(const int* __restrict__ rowptr, const int* __restrict__ csr,
                            const float* __restrict__ dis, const float* __restrict__ q,
                            const float* __restrict__ c, int k,
                            float* __restrict__ qnext, float* __restrict__ vacc,
                            int n, int first) {
    int tid = blockIdx.x * blockDim.x + threadIdx.x;
    int node = tid >> 4;
    int lane = tid & 15;
    if (node >= n) return;
    int beg = rowptr[node], end = rowptr[node + 1];
    float acc = 0.f;
    for (int e = beg + lane; e < end; e += 16) acc += q[csr[e]];
    for (int off = 8; off > 0; off >>= 1) acc += __shfl_down(acc, off, 16);
    if (lane == 0) {
        float d = dis[node];
        float p = d * (acc + q[node]);
        qnext[node] = d * p;
        float add = c[k] * p;
        vacc[node] = first ? (c[0] + add) : (vacc[node] + add);
    }
}

// ---------- min-max normalize ----------
__global__ void minmax_part_kernel(const float* __restrict__ v, int n,
                                   float* __restrict__ bmin, float* __restrict__ bmax) {
    __shared__ float smn[TPB], smx[TPB];
    int t = threadIdx.x;
    float mn = 1e30f, mx = -1e30f;
    for (int i = blockIdx.x * blockDim.x + t; i < n; i += gridDim.x * blockDim.x) {
        float x = v[i];
        mn = fminf(mn, x);
        mx = fmaxf(mx, x);
    }
    smn[t] = mn; smx[t] = mx;
    __syncthreads();
    for (int s = TPB / 2; s > 0; s >>= 1) {
        if (t < s) { smn[t] = fminf(smn[t], smn[t + s]); smx[t] = fmaxf(smx[t], smx[t + s]); }
        __syncthreads();
    }
    if (t == 0) { bmin[blockIdx.x] = smn[0]; bmax[blockIdx.x] = smx[0]; }
}

__global__ void minmax_final_kernel(const float* __restrict__ bmin, const float* __restrict__ bmax,
                                    int nblk, float* __restrict__ mnmx) {
    __shared__ float smn[TPB], smx[TPB];
    int t = threadIdx.x;
    float mn = 1e30f, mx = -1e30f;
    for (int i = t; i < nblk; i += TPB) {
        mn = fminf(mn, bmin[i]);
        mx = fmaxf(mx, bmax[i]);
    }
    smn[t] = mn; smx[t] = mx;
    __syncthreads();
    for (int s = TPB / 2; s > 0; s >>= 1) {
        if (t < s) { smn[t] = fminf(smn[t], smn[t + s]); smx[t] = fmaxf(smx[t], smx[t + s]); }
        __syncthreads();
    }
    if (t == 0) { mnmx[0] = smn[0]; mnmx[1] = smx[0]; }
}

__global__ void normalize_kernel(const float* __restrict__ v, const float* __restrict__ mnmx,
                                 float* __restrict__ out, int n) {
    int i = blockIdx.x * blockDim.x + threadIdx.x;
    if (i < n) {
        float mn = mnmx[0], mx = mnmx[1];
        out[i] = (v[i] - mn) / (mx - mn + 1e-15f);
    }
}

static inline int cdiv(long long a, int b) { return (int)((a + b - 1) / b); }

extern "C" void kernel_launch(void* const* d_in, const int* in_sizes, int n_in,
                              void* d_out, int out_size, void* d_ws, size_t ws_size,
                              hipStream_t stream) {
    const int N = out_size;               // 100000
    const int E = in_sizes[0] / 2;        // 3200000
    const int* src = (const int*)d_in[0];
    const int* dst = src + E;

    const float* W1 = (const float*)d_in[1];  const float* b1 = (const float*)d_in[2];
    const float* W2 = (const float*)d_in[3];  const float* b2 = (const float*)d_in[4];
    const float* W3 = (const float*)d_in[5];  const float* b3 = (const float*)d_in[6];
    const float* W4 = (const float*)d_in[7];  const float* b4 = (const float*)d_in[8];
    const float* W5 = (const float*)d_in[9];  const float* b5 = (const float*)d_in[10];
    const float* W6 = (const float*)d_in[11]; const float* b6 = (const float*)d_in[12];

    const int nb = cdiv(N, TPB);          // scan blocks (391 <= 512)

    // workspace layout
    char* p = (char*)d_ws;
    int*   degi   = (int*)p;   p += (size_t)N * 4;
    int*   rowptr = (int*)p;   p += (size_t)(N + 1) * 4;
    int*   cursor = (int*)p;   p += (size_t)N * 4;
    int*   bsum   = (int*)p;   p += (size_t)512 * 4;
    int*   csr    = (int*)p;   p += (size_t)E * 4;
    float* dis    = (float*)p; p += (size_t)N * 4;
    float* qA     = (float*)p; p += (size_t)N * 4;
    float* qB     = (float*)p; p += (size_t)N * 4;
    float* vacc   = (float*)p; p += (size_t)N * 4;
    float* c      = (float*)p; p += (size_t)8 * 4;
    float* bmin   = (float*)p; p += (size_t)TPB * 4;
    float* bmax   = (float*)p; p += (size_t)TPB * 4;
    float* mnmx   = (float*)p; p += 2 * 4;

    // ---- CSR build ----
    hipMemsetAsync(degi, 0, (size_t)N * 4, stream);
    deg_int_kernel<<<cdiv(E, TPB), TPB, 0, stream>>>(dst, E, degi);
    scan_part<<<nb, TPB, 0, stream>>>(degi, N, bsum);
    scan_bsum_block<<<1, 512, 0, stream>>>(bsum, nb);
    scan_final<<<nb, TPB, 0, stream>>>(degi, N, bsum, rowptr, cursor, dis);
    fill_csr<<<cdiv(E, TPB), TPB, 0, stream>>>(src, dst, E, cursor, csr);

    // ---- feature-side coefficients ----
    coef_kernel<<<1, 128, 0, stream>>>(W1, b1, W2, b2, W3, b3, W4, b4, W5, b5, W6, b6, c);

    // ---- 6 scalar aggregations: p_k = A_norm p_{k-1}, accumulate c_k * p_k ----
    const int gblocks = cdiv((long long)N * 16, TPB);
    // k=1: q = dis (= dis .* p0, p0 = ones)
    gather_step<<<gblocks, TPB, 0, stream>>>(rowptr, csr, dis, dis, c, 1, qA, vacc, N, 1);
    gather_step<<<gblocks, TPB, 0, stream>>>(rowptr, csr, dis, qA,  c, 2, qB, vacc, N, 0);
    gather_step<<<gblocks, TPB, 0, stream>>>(rowptr, csr, dis, qB,  c, 3, qA, vacc, N, 0);
    gather_step<<<gblocks, TPB, 0, stream>>>(rowptr, csr, dis, qA,  c, 4, qB, vacc, N, 0);
    gather_step<<<gblocks, TPB, 0, stream>>>(rowptr, csr, dis, qB,  c, 5, qA, vacc, N, 0);
    gather_step<<<gblocks, TPB, 0, stream>>>(rowptr, csr, dis, qA,  c, 6, qB, vacc, N, 0);

    // ---- min-max normalize ----
    minmax_part_kernel<<<TPB, TPB, 0, stream>>>(vacc, N, bmin, bmax);
    minmax_final_kernel<<<1, TPB, 0, stream>>>(bmin, bmax, TPB, mnmx);
    normalize_kernel<<<cdiv(N, TPB), TPB, 0, stream>>>(vacc, mnmx, (float*)d_out, N);
}

// Round 4
// 272.856 us; speedup vs baseline: 25.5877x; 2.1456x over previous
//
#include <hip/hip_runtime.h>

// GCN 6-layer, N=100k, E=3.2M — Krylov form + locality-binned CSR build.
// v = sum_{k=0..6} c_k * p_k, p_k = A_norm^k 1. Node side: 6 scalar gathers
// over CSR. CSR built via 256-node bucket binning (counting sort): histogram
// -> scan -> bin pairs -> per-bucket LDS scatter + coalesced csr write.

#define TPB 256
#define NBPAD 400        // >= nb=391 buckets
#define STAGE_CAP 12288  // per-bucket csr LDS stage (mean 8192, sigma ~90)

// ---------- CSR build ----------
__global__ void hist_kernel(const int* __restrict__ dst, int E,
                            int* __restrict__ bucket_cnt, int nb) {
    __shared__ int h[NBPAD];
    for (int j = threadIdx.x; j < NBPAD; j += blockDim.x) h[j] = 0;
    __syncthreads();
    for (long long e = (long long)blockIdx.x * blockDim.x + threadIdx.x; e < E;
         e += (long long)gridDim.x * blockDim.x)
        atomicAdd(&h[dst[e] >> 8], 1);
    __syncthreads();
    for (int j = threadIdx.x; j < nb; j += blockDim.x)
        if (h[j]) atomicAdd(&bucket_cnt[j], h[j]);
}

// exclusive scan of nb (<512) bucket counts; init cursor; rowptr[n]=E
__global__ void bucket_scan(const int* __restrict__ bucket_cnt, int nb,
                            int* __restrict__ bucket_base, int* __restrict__ bucket_cursor,
                            int* __restrict__ rowptr, int n, int E) {
    __shared__ int s[512];
    int t = threadIdx.x;
    int v = (t < nb) ? bucket_cnt[t] : 0;
    s[t] = v;
    __syncthreads();
    for (int off = 1; off < 512; off <<= 1) {
        int a = (t >= off) ? s[t - off] : 0;
        __syncthreads();
        s[t] += a;
        __syncthreads();
    }
    if (t < nb) {
        int ex = s[t] - v;
        bucket_base[t] = ex;
        bucket_cursor[t] = ex;
    }
    if (t == 0) { bucket_base[nb] = E; rowptr[n] = E; }
}

// bin edges into bucket-contiguous packed pairs: hi32 = dst&255, lo32 = src
__global__ __launch_bounds__(256) void binA_kernel(
    const int* __restrict__ src, const int* __restrict__ dst, int E,
    int* __restrict__ bucket_cursor, unsigned long long* __restrict__ binned) {
    __shared__ int cnt[NBPAD];
    __shared__ int cur[NBPAD];
    int t = threadIdx.x;
    long long base = (long long)blockIdx.x * 4096;
    for (int j = t; j < NBPAD; j += 256) cnt[j] = 0;
    __syncthreads();
    int mysrc[16], mydst[16];
#pragma unroll
    for (int j = 0; j < 16; ++j) {
        long long e = base + j * 256 + t;          // coalesced
        if (e < E) {
            mysrc[j] = src[e];
            mydst[j] = dst[e];
            atomicAdd(&cnt[mydst[j] >> 8], 1);
        } else mydst[j] = -1;
    }
    __syncthreads();
    for (int j = t; j < NBPAD; j += 256) {
        int c = cnt[j];
        cur[j] = c > 0 ? atomicAdd(&bucket_cursor[j], c) : 0;
    }
    __syncthreads();
#pragma unroll
    for (int j = 0; j < 16; ++j) {
        if (mydst[j] >= 0) {
            int b = mydst[j] >> 8;
            int pos = atomicAdd(&cur[b], 1);
            binned[pos] = ((unsigned long long)(unsigned)(mydst[j] & 255) << 32)
                          | (unsigned)mysrc[j];
        }
    }
}

// one block per bucket: LDS deg histogram + scan -> rowptr/dis/cursors,
// scatter src into LDS stage, coalesced csr write
__global__ __launch_bounds__(256) void csrB_kernel(
    const unsigned long long* __restrict__ binned,
    const int* __restrict__ bucket_base, int n,
    int* __restrict__ rowptr, int* __restrict__ csr, float* __restrict__ dis) {
    __shared__ int deg[256];
    __shared__ int ex[256];
    __shared__ int cur[256];
    __shared__ int stage[STAGE_CAP];
    int b = blockIdx.x;
    int t = threadIdx.x;
    int ebase = bucket_base[b], eend = bucket_base[b + 1];
    int esize = eend - ebase;
    int gnode = (b << 8) + t;
    deg[t] = 0;
    __syncthreads();
    for (int e = ebase + t; e < eend; e += 256)
        atomicAdd(&deg[(int)(binned[e] >> 32)], 1);
    __syncthreads();
    int d = deg[t];
    ex[t] = d;
    __syncthreads();
    for (int off = 1; off < 256; off <<= 1) {
        int a = (t >= off) ? ex[t - off] : 0;
        __syncthreads();
        ex[t] += a;
        __syncthreads();
    }
    int excl = ex[t] - d;
    if (gnode < n) {
        rowptr[gnode] = ebase + excl;
        dis[gnode] = rsqrtf((float)d + 1.0f);   // +1 = self-loop
    }
    cur[t] = excl;
    __syncthreads();
    if (esize <= STAGE_CAP) {
        for (int e = ebase + t; e < eend; e += 256) {
            unsigned long long pk = binned[e];
            int pos = atomicAdd(&cur[(int)(pk >> 32)], 1);
            stage[pos] = (int)(unsigned)(pk & 0xffffffffu);
        }
        __syncthreads();
        for (int e = t; e < esize; e += 256) csr[ebase + e] = stage[e];
    } else {  // statistical-impossibility fallback, keeps any input correct
        for (int e = ebase + t; e < eend; e += 256) {
            unsigned long long pk = binned[e];
            int pos = atomicAdd(&cur[(int)(pk >> 32)], 1);
            csr[ebase + pos] = (int)(unsigned)(pk & 0xffffffffu);
        }
    }
}

// ---------- coefficient chain (feature side), one block of 128 ----------
__global__ void coef_kernel(const float* __restrict__ W1, const float* __restrict__ b1,
                            const float* __restrict__ W2, const float* __restrict__ b2,
                            const float* __restrict__ W3, const float* __restrict__ b3,
                            const float* __restrict__ W4, const float* __restrict__ b4,
                            const float* __restrict__ W5, const float* __restrict__ b5,
                            const float* __restrict__ W6, const float* __restrict__ b6,
                            float* __restrict__ c) {
    __shared__ float A[6][125];
    __shared__ float B[6][125];
    __shared__ float red[128];
    int t = threadIdx.x;   // 128 threads
    if (t < 25) { A[1][t] = W1[t]; A[0][t] = b1[t]; }
    __syncthreads();
    if (t < 125) {
        for (int k = 0; k < 2; ++k) {
            float s = 0.f;
            for (int i = 0; i < 25; ++i) s += W2[i * 125 + t] * A[k][i];
            B[k + 1][t] = s;
        }
        B[0][t] = b2[t];
    }
    __syncthreads();
    if (t < 125) {
        for (int k = 0; k < 3; ++k) {
            float s = 0.f;
            for (int i = 0; i < 125; ++i) s += W3[i * 125 + t] * B[k][i];
            A[k + 1][t] = s;
        }
        A[0][t] = b3[t];
    }
    __syncthreads();
    if (t < 125) {
        for (int k = 0; k < 4; ++k) {
            float s = 0.f;
            for (int i = 0; i < 125; ++i) s += W4[i * 125 + t] * A[k][i];
            B[k + 1][t] = s;
        }
        B[0][t] = b4[t];
    }
    __syncthreads();
    if (t < 125) {
        for (int k = 0; k < 5; ++k) {
            float s = 0.f;
            for (int i = 0; i < 125; ++i) s += W5[i * 125 + t] * B[k][i];
            A[k + 1][t] = s;
        }
        A[0][t] = b5[t];
    }
    __syncthreads();
    float w6 = (t < 125) ? W6[t] : 0.f;
    for (int k = 0; k < 6; ++k) {
        red[t] = (t < 125) ? w6 * A[k][t] : 0.f;
        __syncthreads();
        for (int off = 64; off > 0; off >>= 1) {
            if (t < off) red[t] += red[t + off];
            __syncthreads();
        }
        if (t == 0) c[k + 1] = red[0];
        __syncthreads();
    }
    if (t == 0) c[0] = b6[0];
}

// ---------- scalar aggregation step ----------
__global__ void gather_step(const int* __restrict__ rowptr, const int* __restrict__ csr,
                            const float* __restrict__ dis, const float* __restrict__ q,
                            const float* __restrict__ c, int k,
                            float* __restrict__ qnext, float* __restrict__ vacc,
                            int n, int first) {
    int tid = blockIdx.x * blockDim.x + threadIdx.x;
    int node = tid >> 4;
    int lane = tid & 15;
    if (node >= n) return;
    int beg = rowptr[node], end = rowptr[node + 1];
    float acc = 0.f;
    for (int e = beg + lane; e < end; e += 16) acc += q[csr[e]];
    for (int off = 8; off > 0; off >>= 1) acc += __shfl_down(acc, off, 16);
    if (lane == 0) {
        float d = dis[node];
        float p = d * (acc + q[node]);
        qnext[node] = d * p;
        float add = c[k] * p;
        vacc[node] = first ? (c[0] + add) : (vacc[node] + add);
    }
}

// ---------- min-max normalize ----------
__global__ void minmax_part_kernel(const float* __restrict__ v, int n,
                                   float* __restrict__ bmin, float* __restrict__ bmax) {
    __shared__ float smn[TPB], smx[TPB];
    int t = threadIdx.x;
    float mn = 1e30f, mx = -1e30f;
    for (int i = blockIdx.x * blockDim.x + t; i < n; i += gridDim.x * blockDim.x) {
        float x = v[i];
        mn = fminf(mn, x);
        mx = fmaxf(mx, x);
    }
    smn[t] = mn; smx[t] = mx;
    __syncthreads();
    for (int s = TPB / 2; s > 0; s >>= 1) {
        if (t < s) { smn[t] = fminf(smn[t], smn[t + s]); smx[t] = fmaxf(smx[t], smx[t + s]); }
        __syncthreads();
    }
    if (t == 0) { bmin[blockIdx.x] = smn[0]; bmax[blockIdx.x] = smx[0]; }
}

__global__ void minmax_final_kernel(const float* __restrict__ bmin, const float* __restrict__ bmax,
                                    int nblk, float* __restrict__ mnmx) {
    __shared__ float smn[TPB], smx[TPB];
    int t = threadIdx.x;
    float mn = 1e30f, mx = -1e30f;
    for (int i = t; i < nblk; i += TPB) {
        mn = fminf(mn, bmin[i]);
        mx = fmaxf(mx, bmax[i]);
    }
    smn[t] = mn; smx[t] = mx;
    __syncthreads();
    for (int s = TPB / 2; s > 0; s >>= 1) {
        if (t < s) { smn[t] = fminf(smn[t], smn[t + s]); smx[t] = fmaxf(smx[t], smx[t + s]); }
        __syncthreads();
    }
    if (t == 0) { mnmx[0] = smn[0]; mnmx[1] = smx[0]; }
}

__global__ void normalize_kernel(const float* __restrict__ v, const float* __restrict__ mnmx,
                                 float* __restrict__ out, int n) {
    int i = blockIdx.x * blockDim.x + threadIdx.x;
    if (i < n) {
        float mn = mnmx[0], mx = mnmx[1];
        out[i] = (v[i] - mn) / (mx - mn + 1e-15f);
    }
}

static inline int cdiv(long long a, int b) { return (int)((a + b - 1) / b); }

extern "C" void kernel_launch(void* const* d_in, const int* in_sizes, int n_in,
                              void* d_out, int out_size, void* d_ws, size_t ws_size,
                              hipStream_t stream) {
    const int N = out_size;               // 100000
    const int E = in_sizes[0] / 2;        // 3200000
    const int* src = (const int*)d_in[0];
    const int* dst = src + E;

    const float* W1 = (const float*)d_in[1];  const float* b1 = (const float*)d_in[2];
    const float* W2 = (const float*)d_in[3];  const float* b2 = (const float*)d_in[4];
    const float* W3 = (const float*)d_in[5];  const float* b3 = (const float*)d_in[6];
    const float* W4 = (const float*)d_in[7];  const float* b4 = (const float*)d_in[8];
    const float* W5 = (const float*)d_in[9];  const float* b5 = (const float*)d_in[10];
    const float* W6 = (const float*)d_in[11]; const float* b6 = (const float*)d_in[12];

    const int nb = (N + 255) >> 8;        // 391 buckets of 256 nodes

    // workspace layout
    char* p = (char*)d_ws;
    int*   bucket_cnt    = (int*)p;   p += (size_t)512 * 4;
    int*   bucket_base   = (int*)p;   p += (size_t)512 * 4;
    int*   bucket_cursor = (int*)p;   p += (size_t)512 * 4;
    int*   rowptr        = (int*)p;   p += (size_t)(N + 1) * 4;
    int*   csr           = (int*)p;   p += (size_t)E * 4;
    unsigned long long* binned = (unsigned long long*)p; p += (size_t)E * 8;
    float* dis    = (float*)p; p += (size_t)N * 4;
    float* qA     = (float*)p; p += (size_t)N * 4;
    float* qB     = (float*)p; p += (size_t)N * 4;
    float* vacc   = (float*)p; p += (size_t)N * 4;
    float* c      = (float*)p; p += (size_t)8 * 4;
    float* bmin   = (float*)p; p += (size_t)TPB * 4;
    float* bmax   = (float*)p; p += (size_t)TPB * 4;
    float* mnmx   = (float*)p; p += 2 * 4;

    // ---- CSR build (counting sort by 256-node bucket) ----
    hipMemsetAsync(bucket_cnt, 0, 512 * 4, stream);
    hist_kernel<<<512, TPB, 0, stream>>>(dst, E, bucket_cnt, nb);
    bucket_scan<<<1, 512, 0, stream>>>(bucket_cnt, nb, bucket_base, bucket_cursor,
                                       rowptr, N, E);
    binA_kernel<<<cdiv(E, 4096), 256, 0, stream>>>(src, dst, E, bucket_cursor, binned);
    csrB_kernel<<<nb, 256, 0, stream>>>(binned, bucket_base, N, rowptr, csr, dis);

    // ---- feature-side coefficients ----
    coef_kernel<<<1, 128, 0, stream>>>(W1, b1, W2, b2, W3, b3, W4, b4, W5, b5, W6, b6, c);

    // ---- 6 scalar aggregations ----
    const int gblocks = cdiv((long long)N * 16, TPB);
    gather_step<<<gblocks, TPB, 0, stream>>>(rowptr, csr, dis, dis, c, 1, qA, vacc, N, 1);
    gather_step<<<gblocks, TPB, 0, stream>>>(rowptr, csr, dis, qA,  c, 2, qB, vacc, N, 0);
    gather_step<<<gblocks, TPB, 0, stream>>>(rowptr, csr, dis, qB,  c, 3, qA, vacc, N, 0);
    gather_step<<<gblocks, TPB, 0, stream>>>(rowptr, csr, dis, qA,  c, 4, qB, vacc, N, 0);
    gather_step<<<gblocks, TPB, 0, stream>>>(rowptr, csr, dis, qB,  c, 5, qA, vacc, N, 0);
    gather_step<<<gblocks, TPB, 0, stream>>>(rowptr, csr, dis, qA,  c, 6, qB, vacc, N, 0);

    // ---- min-max normalize ----
    minmax_part_kernel<<<TPB, TPB, 0, stream>>>(vacc, N, bmin, bmax);
    minmax_final_kernel<<<1, TPB, 0, stream>>>(bmin, bmax, TPB, mnmx);
    normalize_kernel<<<cdiv(N, TPB), TPB, 0, stream>>>(vacc, mnmx, (float*)d_out, N);
}

// Round 5
// 220.142 us; speedup vs baseline: 31.7147x; 1.2395x over previous
//
#include <hip/hip_runtime.h>

// GCN 6-layer, N=100k, E=3.2M — Krylov form + binned CSR build.
// v = sum_{k=0..6} c_k * p_k, p_k = A_norm^k 1.
// Round 4: coef chain merged into hist launch (hidden), binned pairs packed
// to 4B (dst_local<<24 | src).

#define TPB 256
#define NBPAD 400        // >= nb=391 buckets
#define STAGE_CAP 12288  // per-bucket csr LDS stage (mean 8192, sigma ~90)

// ---------- coefficient chain helpers (256 threads, block-level) ----------
// out[k+1][t] = sum_i W[i*125+t] * in[k][i]  (k < NK);  out[0][t] = bias[t]
template <int NK, int DIN>
__device__ void coef_step(const float* __restrict__ W, const float* __restrict__ bias,
                          const float (*in)[128], float (*out)[128],
                          float (*part)[6][128], int tid) {
    int t = tid & 127, half = tid >> 7;
    int i0 = half ? (DIN / 2) : 0;
    int i1 = half ? DIN : (DIN / 2);
    float s[NK];
#pragma unroll
    for (int k = 0; k < NK; ++k) s[k] = 0.f;
    if (t < 125) {
#pragma unroll 4
        for (int i = i0; i < i1; ++i) {
            float w = W[i * 125 + t];
#pragma unroll
            for (int k = 0; k < NK; ++k) s[k] += w * in[k][i];
        }
    }
#pragma unroll
    for (int k = 0; k < NK; ++k) part[half][k][t] = s[k];
    __syncthreads();
    if (half == 0 && t < 125) {
#pragma unroll
        for (int k = 0; k < NK; ++k) out[k + 1][t] = part[0][k][t] + part[1][k][t];
        out[0][t] = bias[t];
    }
    __syncthreads();
}

// ---------- merged histogram + coefficient kernel ----------
// blocks 0..nbh-1: bucket histogram of dst>>8. last block: coefficient chain.
__global__ __launch_bounds__(256) void hist_coef_kernel(
    const int* __restrict__ dst, int E, int* __restrict__ bucket_cnt, int nb,
    const float* __restrict__ W1, const float* __restrict__ b1,
    const float* __restrict__ W2, const float* __restrict__ b2,
    const float* __restrict__ W3, const float* __restrict__ b3,
    const float* __restrict__ W4, const float* __restrict__ b4,
    const float* __restrict__ W5, const float* __restrict__ b5,
    const float* __restrict__ W6, const float* __restrict__ b6,
    float* __restrict__ c) {
    __shared__ int h[NBPAD];
    __shared__ float A[6][128];
    __shared__ float B[6][128];
    __shared__ float part[2][6][128];
    int t = threadIdx.x;
    int nbh = gridDim.x - 1;

    if ((int)blockIdx.x < nbh) {
        // ---- histogram ----
        for (int j = t; j < NBPAD; j += 256) h[j] = 0;
        __syncthreads();
        for (long long e = (long long)blockIdx.x * 256 + t; e < E;
             e += (long long)nbh * 256)
            atomicAdd(&h[dst[e] >> 8], 1);
        __syncthreads();
        for (int j = t; j < nb; j += 256)
            if (h[j]) atomicAdd(&bucket_cnt[j], h[j]);
        return;
    }

    // ---- coefficient chain ----
    // layer 1 state: A[1] = W1 (25), A[0] = b1
    if (t < 25) { A[1][t] = W1[t]; A[0][t] = b1[t]; }
    __syncthreads();
    coef_step<2, 25>(W2, b2, A, B, part, t);    // layer 2: 25 -> 125
    coef_step<3, 125>(W3, b3, B, A, part, t);   // layer 3
    coef_step<4, 125>(W4, b4, A, B, part, t);   // layer 4
    coef_step<5, 125>(W5, b5, B, A, part, t);   // layer 5
    // layer 6: c[k+1] = W6 . A[k], k=0..5; waves handle k = wave, wave+4
    int wave = t >> 6, lane = t & 63;
#pragma unroll
    for (int rep = 0; rep < 2; ++rep) {
        int k = wave + rep * 4;
        if (k < 6) {
            float acc = (lane < 125 ? W6[lane] * A[k][lane] : 0.f)
                      + (lane + 64 < 125 ? W6[lane + 64] * A[k][lane + 64] : 0.f);
            for (int off = 32; off > 0; off >>= 1) acc += __shfl_down(acc, off);
            if (lane == 0) c[k + 1] = acc;
        }
    }
    if (t == 0) c[0] = b6[0];
}

// exclusive scan of nb (<512) bucket counts; init cursor; rowptr[n]=E
__global__ void bucket_scan(const int* __restrict__ bucket_cnt, int nb,
                            int* __restrict__ bucket_base, int* __restrict__ bucket_cursor,
                            int* __restrict__ rowptr, int n, int E) {
    __shared__ int s[512];
    int t = threadIdx.x;
    int v = (t < nb) ? bucket_cnt[t] : 0;
    s[t] = v;
    __syncthreads();
    for (int off = 1; off < 512; off <<= 1) {
        int a = (t >= off) ? s[t - off] : 0;
        __syncthreads();
        s[t] += a;
        __syncthreads();
    }
    if (t < nb) {
        int ex = s[t] - v;
        bucket_base[t] = ex;
        bucket_cursor[t] = ex;
    }
    if (t == 0) { bucket_base[nb] = E; rowptr[n] = E; }
}

// bin edges into bucket-contiguous packed words: (dst&255)<<24 | src  (src<2^24)
__global__ __launch_bounds__(256) void binA_kernel(
    const int* __restrict__ src, const int* __restrict__ dst, int E,
    int* __restrict__ bucket_cursor, unsigned int* __restrict__ binned) {
    __shared__ int cnt[NBPAD];
    __shared__ int cur[NBPAD];
    int t = threadIdx.x;
    long long base = (long long)blockIdx.x * 4096;
    for (int j = t; j < NBPAD; j += 256) cnt[j] = 0;
    __syncthreads();
    int mysrc[16], mydst[16];
#pragma unroll
    for (int j = 0; j < 16; ++j) {
        long long e = base + j * 256 + t;          // coalesced
        if (e < E) {
            mysrc[j] = src[e];
            mydst[j] = dst[e];
            atomicAdd(&cnt[mydst[j] >> 8], 1);
        } else mydst[j] = -1;
    }
    __syncthreads();
    for (int j = t; j < NBPAD; j += 256) {
        int cx = cnt[j];
        cur[j] = cx > 0 ? atomicAdd(&bucket_cursor[j], cx) : 0;
    }
    __syncthreads();
#pragma unroll
    for (int j = 0; j < 16; ++j) {
        if (mydst[j] >= 0) {
            int b = mydst[j] >> 8;
            int pos = atomicAdd(&cur[b], 1);
            binned[pos] = ((unsigned)(mydst[j] & 255) << 24) | (unsigned)mysrc[j];
        }
    }
}

// one block per bucket: LDS deg histogram + scan -> rowptr/dis/cursors,
// scatter src into LDS stage, coalesced csr write
__global__ __launch_bounds__(256) void csrB_kernel(
    const unsigned int* __restrict__ binned,
    const int* __restrict__ bucket_base, int n,
    int* __restrict__ rowptr, int* __restrict__ csr, float* __restrict__ dis) {
    __shared__ int deg[256];
    __shared__ int ex[256];
    __shared__ int cur[256];
    __shared__ int stage[STAGE_CAP];
    int b = blockIdx.x;
    int t = threadIdx.x;
    int ebase = bucket_base[b], eend = bucket_base[b + 1];
    int esize = eend - ebase;
    int gnode = (b << 8) + t;
    deg[t] = 0;
    __syncthreads();
    for (int e = ebase + t; e < eend; e += 256)
        atomicAdd(&deg[binned[e] >> 24], 1);
    __syncthreads();
    int d = deg[t];
    ex[t] = d;
    __syncthreads();
    for (int off = 1; off < 256; off <<= 1) {
        int a = (t >= off) ? ex[t - off] : 0;
        __syncthreads();
        ex[t] += a;
        __syncthreads();
    }
    int excl = ex[t] - d;
    if (gnode < n) {
        rowptr[gnode] = ebase + excl;
        dis[gnode] = rsqrtf((float)d + 1.0f);   // +1 = self-loop
    }
    cur[t] = excl;
    __syncthreads();
    if (esize <= STAGE_CAP) {
        for (int e = ebase + t; e < eend; e += 256) {
            unsigned int pk = binned[e];
            int pos = atomicAdd(&cur[pk >> 24], 1);
            stage[pos] = (int)(pk & 0xffffffu);
        }
        __syncthreads();
        for (int e = t; e < esize; e += 256) csr[ebase + e] = stage[e];
    } else {  // statistical-impossibility fallback, keeps any input correct
        for (int e = ebase + t; e < eend; e += 256) {
            unsigned int pk = binned[e];
            int pos = atomicAdd(&cur[pk >> 24], 1);
            csr[ebase + pos] = (int)(pk & 0xffffffu);
        }
    }
}

// ---------- scalar aggregation step ----------
__global__ void gather_step(const int* __restrict__ rowptr, const int* __restrict__ csr,
                            const float* __restrict__ dis, const float* __restrict__ q,
                            const float* __restrict__ c, int k,
                            float* __restrict__ qnext, float* __restrict__ vacc,
                            int n, int first) {
    int tid = blockIdx.x * blockDim.x + threadIdx.x;
    int node = tid >> 4;
    int lane = tid & 15;
    if (node >= n) return;
    int beg = rowptr[node], end = rowptr[node + 1];
    float acc = 0.f;
    for (int e = beg + lane; e < end; e += 16) acc += q[csr[e]];
    for (int off = 8; off > 0; off >>= 1) acc += __shfl_down(acc, off, 16);
    if (lane == 0) {
        float d = dis[node];
        float p = d * (acc + q[node]);
        qnext[node] = d * p;
        float add = c[k] * p;
        vacc[node] = first ? (c[0] + add) : (vacc[node] + add);
    }
}

// ---------- min-max normalize ----------
__global__ void minmax_part_kernel(const float* __restrict__ v, int n,
                                   float* __restrict__ bmin, float* __restrict__ bmax) {
    __shared__ float smn[TPB], smx[TPB];
    int t = threadIdx.x;
    float mn = 1e30f, mx = -1e30f;
    for (int i = blockIdx.x * blockDim.x + t; i < n; i += gridDim.x * blockDim.x) {
        float x = v[i];
        mn = fminf(mn, x);
        mx = fmaxf(mx, x);
    }
    smn[t] = mn; smx[t] = mx;
    __syncthreads();
    for (int s = TPB / 2; s > 0; s >>= 1) {
        if (t < s) { smn[t] = fminf(smn[t], smn[t + s]); smx[t] = fmaxf(smx[t], smx[t + s]); }
        __syncthreads();
    }
    if (t == 0) { bmin[blockIdx.x] = smn[0]; bmax[blockIdx.x] = smx[0]; }
}

__global__ void minmax_final_kernel(const float* __restrict__ bmin, const float* __restrict__ bmax,
                                    int nblk, float* __restrict__ mnmx) {
    __shared__ float smn[TPB], smx[TPB];
    int t = threadIdx.x;
    float mn = 1e30f, mx = -1e30f;
    for (int i = t; i < nblk; i += TPB) {
        mn = fminf(mn, bmin[i]);
        mx = fmaxf(mx, bmax[i]);
    }
    smn[t] = mn; smx[t] = mx;
    __syncthreads();
    for (int s = TPB / 2; s > 0; s >>= 1) {
        if (t < s) { smn[t] = fminf(smn[t], smn[t + s]); smx[t] = fmaxf(smx[t], smx[t + s]); }
        __syncthreads();
    }
    if (t == 0) { mnmx[0] = smn[0]; mnmx[1] = smx[0]; }
}

__global__ void normalize_kernel(const float* __restrict__ v, const float* __restrict__ mnmx,
                                 float* __restrict__ out, int n) {
    int i = blockIdx.x * blockDim.x + threadIdx.x;
    if (i < n) {
        float mn = mnmx[0], mx = mnmx[1];
        out[i] = (v[i] - mn) / (mx - mn + 1e-15f);
    }
}

static inline int cdiv(long long a, int b) { return (int)((a + b - 1) / b); }

extern "C" void kernel_launch(void* const* d_in, const int* in_sizes, int n_in,
                              void* d_out, int out_size, void* d_ws, size_t ws_size,
                              hipStream_t stream) {
    const int N = out_size;               // 100000
    const int E = in_sizes[0] / 2;        // 3200000
    const int* src = (const int*)d_in[0];
    const int* dst = src + E;

    const float* W1 = (const float*)d_in[1];  const float* b1 = (const float*)d_in[2];
    const float* W2 = (const float*)d_in[3];  const float* b2 = (const float*)d_in[4];
    const float* W3 = (const float*)d_in[5];  const float* b3 = (const float*)d_in[6];
    const float* W4 = (const float*)d_in[7];  const float* b4 = (const float*)d_in[8];
    const float* W5 = (const float*)d_in[9];  const float* b5 = (const float*)d_in[10];
    const float* W6 = (const float*)d_in[11]; const float* b6 = (const float*)d_in[12];

    const int nb = (N + 255) >> 8;        // 391 buckets of 256 nodes

    // workspace layout
    char* p = (char*)d_ws;
    int*   bucket_cnt    = (int*)p;   p += (size_t)512 * 4;
    int*   bucket_base   = (int*)p;   p += (size_t)512 * 4;
    int*   bucket_cursor = (int*)p;   p += (size_t)512 * 4;
    int*   rowptr        = (int*)p;   p += (size_t)(N + 1) * 4;
    int*   csr           = (int*)p;   p += (size_t)E * 4;
    unsigned int* binned = (unsigned int*)p; p += (size_t)E * 4;
    float* dis    = (float*)p; p += (size_t)N * 4;
    float* qA     = (float*)p; p += (size_t)N * 4;
    float* qB     = (float*)p; p += (size_t)N * 4;
    float* vacc   = (float*)p; p += (size_t)N * 4;
    float* c      = (float*)p; p += (size_t)8 * 4;
    float* bmin   = (float*)p; p += (size_t)TPB * 4;
    float* bmax   = (float*)p; p += (size_t)TPB * 4;
    float* mnmx   = (float*)p; p += 2 * 4;

    // ---- CSR build + coefficients (coef hidden in hist launch) ----
    hipMemsetAsync(bucket_cnt, 0, 512 * 4, stream);
    hist_coef_kernel<<<513, 256, 0, stream>>>(dst, E, bucket_cnt, nb,
                                              W1, b1, W2, b2, W3, b3,
                                              W4, b4, W5, b5, W6, b6, c);
    bucket_scan<<<1, 512, 0, stream>>>(bucket_cnt, nb, bucket_base, bucket_cursor,
                                       rowptr, N, E);
    binA_kernel<<<cdiv(E, 4096), 256, 0, stream>>>(src, dst, E, bucket_cursor, binned);
    csrB_kernel<<<nb, 256, 0, stream>>>(binned, bucket_base, N, rowptr, csr, dis);

    // ---- 6 scalar aggregations ----
    const int gblocks = cdiv((long long)N * 16, TPB);
    gather_step<<<gblocks, TPB, 0, stream>>>(rowptr, csr, dis, dis, c, 1, qA, vacc, N, 1);
    gather_step<<<gblocks, TPB, 0, stream>>>(rowptr, csr, dis, qA,  c, 2, qB, vacc, N, 0);
    gather_step<<<gblocks, TPB, 0, stream>>>(rowptr, csr, dis, qB,  c, 3, qA, vacc, N, 0);
    gather_step<<<gblocks, TPB, 0, stream>>>(rowptr, csr, dis, qA,  c, 4, qB, vacc, N, 0);
    gather_step<<<gblocks, TPB, 0, stream>>>(rowptr, csr, dis, qB,  c, 5, qA, vacc, N, 0);
    gather_step<<<gblocks, TPB, 0, stream>>>(rowptr, csr, dis, qA,  c, 6, qB, vacc, N, 0);

    // ---- min-max normalize ----
    minmax_part_kernel<<<TPB, TPB, 0, stream>>>(vacc, N, bmin, bmax);
    minmax_final_kernel<<<1, TPB, 0, stream>>>(bmin, bmax, TPB, mnmx);
    normalize_kernel<<<cdiv(N, TPB), TPB, 0, stream>>>(vacc, mnmx, (float*)d_out, N);
}